// Round 2
// baseline (229.995 us; speedup 1.0000x reference)
//
#include <hip/hip_runtime.h>
#include <hip/hip_bf16.h>

#define B_ROWS 16384
#define D_DIM  1024
#define F_DIM  1031
#define KP     1088   // padded K (17 * 64)
#define NP     1152   // padded N (9 * 128)
#define NT_N   9
#define NT_M   128
#define LDSTR  72     // LDS row stride in elements (pad 64 -> 72)

typedef __attribute__((ext_vector_type(4))) float  f32x4;
typedef __attribute__((ext_vector_type(8))) short  bf16x8;

__device__ __forceinline__ unsigned short f2bf(float f) {
    unsigned int x = __float_as_uint(f);
    unsigned int r = (x + 0x7fffu + ((x >> 16) & 1u)) >> 16;
    return (unsigned short)r;
}

// ---------------- Kernel 1: per-row reductions + linear bf16 feature rows -------------
__global__ __launch_bounds__(256) void k_features(
        const float* __restrict__ h, const float* __restrict__ vc,
        const float* __restrict__ vb, unsigned short* __restrict__ featpad) {
    int row = blockIdx.x;
    int tid = threadIdx.x;
    const float4* h4 = (const float4*)(h  + (size_t)row * D_DIM);
    const float4* c4 = (const float4*)(vc + (size_t)row * D_DIM);
    const float4* b4 = (const float4*)(vb + (size_t)row * D_DIM);
    float4 hv = h4[tid], cv = c4[tid], bv = b4[tid];
    float nc  = cv.x*cv.x + cv.y*cv.y + cv.z*cv.z + cv.w*cv.w;
    float nb  = bv.x*bv.x + bv.y*bv.y + bv.z*bv.z + bv.w*bv.w;
    float dcb = cv.x*bv.x + cv.y*bv.y + cv.z*bv.z + cv.w*bv.w;
    float nh  = hv.x*hv.x + hv.y*hv.y + hv.z*hv.z + hv.w*hv.w;
    #pragma unroll
    for (int o = 32; o > 0; o >>= 1) {
        nc  += __shfl_down(nc,  o);
        nb  += __shfl_down(nb,  o);
        dcb += __shfl_down(dcb, o);
        nh  += __shfl_down(nh,  o);
    }
    __shared__ float red[4][4];
    __shared__ float scal[8];
    int wid = tid >> 6, lane = tid & 63;
    if (lane == 0) { red[wid][0] = nc; red[wid][1] = nb; red[wid][2] = dcb; red[wid][3] = nh; }
    __syncthreads();
    if (tid == 0) {
        float NC = 0, NB = 0, DCB = 0, NH = 0;
        #pragma unroll
        for (int w = 0; w < 4; ++w) { NC += red[w][0]; NB += red[w][1]; DCB += red[w][2]; NH += red[w][3]; }
        float rc = sqrtf(NC), rb = sqrtf(NB), rh = sqrtf(NH);
        float mc = fmaxf(rc, 1e-12f), mb = fmaxf(rb, 1e-12f);
        float align = DCB / (mc * mb);
        float t2 = NC/(mc*mc) - 2.f*DCB/(mc*mb) + NB/(mb*mb);
        t2 = fmaxf(t2, 0.f);
        scal[0] = align;
        scal[1] = sqrtf(t2);
        scal[2] = t2;
        scal[3] = sqrtf(fmaxf(NC - 2.f*DCB + NB, 0.f));
        scal[4] = rc; scal[5] = rb; scal[6] = rh; scal[7] = 0.f;
    }
    __syncthreads();
    unsigned short* orow = featpad + (size_t)row * KP;
    // main part: this thread already holds h elements 4*tid..4*tid+3 in hv
    {
        union { unsigned int u[2]; unsigned short us[4]; } w;
        w.us[0] = f2bf(hv.x); w.us[1] = f2bf(hv.y);
        w.us[2] = f2bf(hv.z); w.us[3] = f2bf(hv.w);
        *(uint2*)(orow + 4 * tid) = *(uint2*)w.u;
    }
    // tail: columns 1024..1087 (7 scalars + zeros)
    if (tid < 8) {
        union { uint4 v; unsigned short us[8]; } pack;
        #pragma unroll
        for (int i = 0; i < 8; ++i) {
            int sc = 1024 + tid * 8 + i;
            float v = (sc < F_DIM) ? scal[sc - D_DIM] : 0.f;
            pack.us[i] = f2bf(v);
        }
        *(uint4*)(orow + 1024 + tid * 8) = pack.v;
    }
}

// ---------------- Kernel 2: W1 -> W1^T bf16, padded, linear ----------------
__global__ __launch_bounds__(256) void k_w1t(const float* __restrict__ W1,
                                             unsigned short* __restrict__ w1t) {
    int idx = blockIdx.x * 256 + threadIdx.x;
    if (idx >= NP * KP) return;
    int n = idx / KP, c = idx % KP;
    float v = 0.f;
    if (n < F_DIM && c < F_DIM) v = W1[(size_t)c * F_DIM + n];
    w1t[idx] = f2bf(v);
}

// ---------------- Kernel 3: GEMM1 (+b1, ReLU) with fused W2 epilogue ----------------
__global__ __launch_bounds__(256) void k_gemm(
        const unsigned short* __restrict__ A,   // featpad [16384][1088]
        const unsigned short* __restrict__ Bt,  // w1t [1152][1088]
        const float* __restrict__ b1, const float* __restrict__ W2,
        float* __restrict__ partials) {
    __shared__ unsigned short As[128 * LDSTR];
    __shared__ unsigned short Bs[128 * LDSTR];
    __shared__ float Hs[128 * 129];
    __shared__ float W2s[128 * 5];
    __shared__ float b1s[128];

    int tid = threadIdx.x;
    int lane = tid & 63;
    int wid = tid >> 6;
    int nt = blockIdx.x, mt = blockIdx.y;

    if (tid < 128) {
        int ncol = nt * 128 + tid;
        bool valid = ncol < F_DIM;
        b1s[tid] = valid ? b1[ncol] : 0.f;
        #pragma unroll
        for (int j = 0; j < 5; ++j) W2s[tid * 5 + j] = valid ? W2[ncol * 5 + j] : 0.f;
    }

    f32x4 acc[4][4] = {};
    int wm = wid >> 1, wn = wid & 1;

    int srow = tid >> 3;        // 0..31
    int scol = (tid & 7) * 8;   // 0,8,..,56 (elements)

    const unsigned short* a_base = A  + ((size_t)(mt * 128) + srow) * KP + scol;
    const unsigned short* b_base = Bt + ((size_t)(nt * 128) + srow) * KP + scol;

    uint4 av[4], bv[4];
    #pragma unroll
    for (int i = 0; i < 4; ++i) {
        av[i] = *(const uint4*)(a_base + (size_t)i * 32 * KP);
        bv[i] = *(const uint4*)(b_base + (size_t)i * 32 * KP);
    }

    for (int kt = 0; kt < KP / 64; ++kt) {
        __syncthreads();   // previous tile's readers done
        #pragma unroll
        for (int i = 0; i < 4; ++i) {
            *(uint4*)&As[(i * 32 + srow) * LDSTR + scol] = av[i];
            *(uint4*)&Bs[(i * 32 + srow) * LDSTR + scol] = bv[i];
        }
        __syncthreads();   // staging complete
        if (kt + 1 < KP / 64) {
            #pragma unroll
            for (int i = 0; i < 4; ++i) {
                av[i] = *(const uint4*)(a_base + (kt + 1) * 64 + (size_t)i * 32 * KP);
                bv[i] = *(const uint4*)(b_base + (kt + 1) * 64 + (size_t)i * 32 * KP);
            }
        }
        #pragma unroll
        for (int kk = 0; kk < 2; ++kk) {
            bf16x8 af[4], bfr[4];
            int klane = kk * 32 + ((lane >> 4) << 3);
            #pragma unroll
            for (int m = 0; m < 4; ++m) {
                int arow = wm * 64 + m * 16 + (lane & 15);
                af[m] = *(const bf16x8*)&As[arow * LDSTR + klane];
            }
            #pragma unroll
            for (int n = 0; n < 4; ++n) {
                int brow = wn * 64 + n * 16 + (lane & 15);
                bfr[n] = *(const bf16x8*)&Bs[brow * LDSTR + klane];
            }
            #pragma unroll
            for (int m = 0; m < 4; ++m)
                #pragma unroll
                for (int n = 0; n < 4; ++n)
                    acc[m][n] = __builtin_amdgcn_mfma_f32_16x16x32_bf16(af[m], bfr[n], acc[m][n], 0, 0, 0);
        }
    }

    // epilogue: hidden = relu(acc + b1) -> LDS fp32 (stride 129)
    #pragma unroll
    for (int m = 0; m < 4; ++m) {
        #pragma unroll
        for (int n = 0; n < 4; ++n) {
            int col = wn * 64 + n * 16 + (lane & 15);
            #pragma unroll
            for (int r = 0; r < 4; ++r) {
                int row = wm * 64 + m * 16 + ((lane >> 4) << 2) + r;
                float v = acc[m][n][r] + b1s[col];
                Hs[row * 129 + col] = fmaxf(v, 0.f);
            }
        }
    }
    __syncthreads();

    // pass2: hidden_tile @ W2_tile -> partials[nt][row][5]
    {
        int r = tid >> 1, hh = tid & 1;
        float sum[5] = {0.f, 0.f, 0.f, 0.f, 0.f};
        const float* hr = Hs + r * 129 + hh * 64;
        #pragma unroll 8
        for (int c2 = 0; c2 < 64; ++c2) {
            float hvv = hr[c2];
            int cg = hh * 64 + c2;
            #pragma unroll
            for (int j = 0; j < 5; ++j) sum[j] += hvv * W2s[cg * 5 + j];
        }
        #pragma unroll
        for (int j = 0; j < 5; ++j) sum[j] += __shfl_xor(sum[j], 1);
        if (hh == 0) {
            size_t base = ((size_t)nt * B_ROWS + (size_t)mt * 128 + r) * 5;
            #pragma unroll
            for (int j = 0; j < 5; ++j) partials[base + j] = sum[j];
        }
    }
}

// ---------------- Kernel 4: reduce partials + b2 ----------------
__global__ __launch_bounds__(256) void k_reduce(const float* __restrict__ partials,
                                                const float* __restrict__ b2,
                                                float* __restrict__ out) {
    int idx = blockIdx.x * 256 + threadIdx.x;
    if (idx >= B_ROWS * 5) return;
    float s = b2[idx % 5];
    #pragma unroll
    for (int t = 0; t < NT_N; ++t) s += partials[(size_t)t * (B_ROWS * 5) + idx];
    out[idx] = s;
}

extern "C" void kernel_launch(void* const* d_in, const int* in_sizes, int n_in,
                              void* d_out, int out_size, void* d_ws, size_t ws_size,
                              hipStream_t stream) {
    const float* h_final   = (const float*)d_in[0];
    const float* v_current = (const float*)d_in[1];
    const float* v_basin   = (const float*)d_in[2];
    const float* W1        = (const float*)d_in[3];
    const float* b1        = (const float*)d_in[4];
    const float* W2        = (const float*)d_in[5];
    const float* b2        = (const float*)d_in[6];
    float* out = (float*)d_out;

    char* ws = (char*)d_ws;
    unsigned short* featpad = (unsigned short*)ws;                       // 16384*1088*2 = 35,651,584 B
    unsigned short* w1t     = (unsigned short*)(ws + 35651584);          // 1152*1088*2  =  2,506,752 B
    float*          parts   = (float*)(ws + 35651584 + 2506752);         // 9*16384*5*4  =  2,949,120 B

    k_features<<<dim3(B_ROWS), dim3(256), 0, stream>>>(h_final, v_current, v_basin, featpad);
    k_w1t<<<dim3((NP * KP) / 256), dim3(256), 0, stream>>>(W1, w1t);
    k_gemm<<<dim3(NT_N, NT_M), dim3(256), 0, stream>>>(featpad, w1t, b1, W2, parts);
    k_reduce<<<dim3((B_ROWS * 5 + 255) / 256), dim3(256), 0, stream>>>(parts, b2, out);
}